// Round 6
// baseline (8231.110 us; speedup 1.0000x reference)
//
#include <hip/hip_runtime.h>
#include <stdint.h>

typedef unsigned short u16;
typedef __attribute__((ext_vector_type(4))) float f32x4;
typedef __attribute__((ext_vector_type(8))) short bf16x8;

#define DEV __device__ __forceinline__
#define NWG 64

DEV u16 f2bf(float f) {
  union { float f; uint32_t u; } v; v.f = f;
  uint32_t r = (v.u + 0x7FFFu + ((v.u >> 16) & 1u)) >> 16;  // RNE
  return (u16)r;
}
DEV float bf2f(u16 h) {
  union { uint32_t u; float f; } v; v.u = ((uint32_t)h) << 16;
  return v.f;
}
DEV float sigmoidf(float x) { return 1.0f / (1.0f + expf(-x)); }

// async global->LDS, 16B per lane; lds base must be wave-uniform (HW adds lane*16)
DEV void gll16(const void* g, void* l) {
  __builtin_amdgcn_global_load_lds((__attribute__((address_space(1))) void*)g,
                                   (__attribute__((address_space(3))) void*)l,
                                   16, 0, 0);
}

// coherent 16B load: sc0 sc1 bypass L1/L2, read fresh from IC (cross-XCD safe)
DEV f32x4 ldg_coh16(const u16* p) {
  f32x4 r;
  asm volatile("global_load_dwordx4 %0, %1, off sc0 sc1"
               : "=&v"(r) : "v"(p) : "memory");
  return r;
}

// ---------------------------------------------------------------------------
// prep kernels
// ---------------------------------------------------------------------------
__global__ void convert_bf16_kernel(const float* __restrict__ in, u16* __restrict__ out, int n) {
  int i = (blockIdx.x * blockDim.x + threadIdx.x) * 4;
  if (i + 3 < n) {
    f32x4 v = *(const f32x4*)(in + i);
    uint64_t pk = (uint64_t)f2bf(v[0]) | ((uint64_t)f2bf(v[1]) << 16) |
                  ((uint64_t)f2bf(v[2]) << 32) | ((uint64_t)f2bf(v[3]) << 48);
    *(uint64_t*)(out + i) = pk;
  }
}

// out(C,R) bf16 = transpose(in(R,C) f32); R,C multiples of 32
__global__ __launch_bounds__(1024) void transpose_to_bf16(
    const float* __restrict__ in, u16* __restrict__ out, int R, int C) {
  __shared__ float tl[32][33];
  const int tx = threadIdx.x, ty = threadIdx.y;
  const int c0 = blockIdx.x * 32, r0 = blockIdx.y * 32;
  tl[ty][tx] = in[(size_t)(r0 + ty) * C + c0 + tx];
  __syncthreads();
  out[(size_t)(c0 + ty) * R + r0 + tx] = f2bf(tl[tx][ty]);
}

// ---------------------------------------------------------------------------
// GEMM: C(MxN) = A(MxK,bf16) @ Bt(NxK,bf16)^T   (m97 structure, 128x128, BK=64)
// mode 0: write Cf(f32) + Cb(bf16), no bias
// mode 1: write Cb(bf16), +bias
// mode 2: write Cf(f32), +bias
// ---------------------------------------------------------------------------
__global__ __launch_bounds__(256) void gemm_bt_kernel(
    const u16* __restrict__ A, const u16* __restrict__ Bt,
    const float* __restrict__ bias,
    float* __restrict__ Cf, u16* __restrict__ Cb,
    int M, int N, int K, int mode) {
  __shared__ u16 As[128 * 64];
  __shared__ u16 Bs[128 * 64];
  const int tid  = threadIdx.x;
  const int lane = tid & 63;
  const int wid  = tid >> 6;
  const int wr   = wid >> 1, wc = wid & 1;
  const size_t arow0 = (size_t)blockIdx.y * 128;
  const size_t brow0 = (size_t)blockIdx.x * 128;

  f32x4 acc[4][4];
#pragma unroll
  for (int m = 0; m < 4; ++m)
#pragma unroll
    for (int n = 0; n < 4; ++n) acc[m][n] = (f32x4){0.f, 0.f, 0.f, 0.f};

  for (int k0 = 0; k0 < K; k0 += 64) {
#pragma unroll
    for (int it = 0; it < 4; ++it) {
      const int slot = it * 4 + wid;
      const int ch   = slot * 64 + lane;
      const int r    = ch >> 3;
      const int cc   = (ch & 7) * 8;
      gll16(A  + (arow0 + r) * K + k0 + cc, (void*)(As + slot * 64 * 8));
      gll16(Bt + (brow0 + r) * K + k0 + cc, (void*)(Bs + slot * 64 * 8));
    }
    __syncthreads();
#pragma unroll
    for (int kk = 0; kk < 2; ++kk) {
      const int ro = lane & 15;
      const int ko = kk * 32 + (lane >> 4) * 8;
      bf16x8 av[4], bv[4];
#pragma unroll
      for (int m = 0; m < 4; ++m) av[m] = *(const bf16x8*)(As + (wr * 64 + m * 16 + ro) * 64 + ko);
#pragma unroll
      for (int n = 0; n < 4; ++n) bv[n] = *(const bf16x8*)(Bs + (wc * 64 + n * 16 + ro) * 64 + ko);
#pragma unroll
      for (int m = 0; m < 4; ++m)
#pragma unroll
        for (int n = 0; n < 4; ++n)
          acc[m][n] = __builtin_amdgcn_mfma_f32_16x16x32_bf16(av[m], bv[n], acc[m][n], 0, 0, 0);
    }
    __syncthreads();
  }

  const int rb = (lane >> 4) * 4;
  const int cn = lane & 15;
#pragma unroll
  for (int m = 0; m < 4; ++m) {
#pragma unroll
    for (int n = 0; n < 4; ++n) {
      const size_t col = brow0 + wc * 64 + n * 16 + cn;
      const float badd = (mode != 0) ? bias[col] : 0.f;
#pragma unroll
      for (int r = 0; r < 4; ++r) {
        const size_t row = arow0 + wr * 64 + m * 16 + rb + r;
        const float v = acc[m][n][r] + badd;
        if (mode == 0) { Cf[row * N + col] = v; Cb[row * N + col] = f2bf(v); }
        else if (mode == 1) { Cb[row * N + col] = f2bf(v); }
        else { Cf[row * N + col] = v; }
      }
    }
  }
}

// ---------------------------------------------------------------------------
// Persistent per-layer LSTM recurrence, Wr-in-registers.
// 64 WGs x 256 thr, 1 WG/CU (launch_bounds(256,1) -> 512 VGPR budget).
// Wave w holds gate w's 16 Wr rows (K=1024) as 32 bf16x8 fragments in regs
// (constant all 256 steps). Per step: poll flags -> coherent gather of 64KB
// h panel -> single swizzled LDS stage -> 32x MFMA (A from LDS, B regs) ->
// gates (c in regs) -> coherent h publish -> flag. 3 barriers/step.
// ---------------------------------------------------------------------------
__global__ __launch_bounds__(256, 1) void lstm_layer_kernel(
    const u16* __restrict__ xgb, const float* __restrict__ xgf, int xg32,
    const u16* __restrict__ wrT,      // (4096,1024) bf16, layer slice
    u16* __restrict__ ys,             // (B*T,1024) bf16; h_t at row b*256+t
    float* __restrict__ out,          // (2,L,B,U) f32
    uint32_t* __restrict__ flags,     // [64], zeroed once per launch
    int l) {
  __shared__ __align__(16) u16 Hs[32 * 1024];   // 64 KB h panel, swizzled
  __shared__ float gl[4][32][17];               // padded: no 4-way b32 conflict

  const int tid  = threadIdx.x;
  const int lane = tid & 63;
  const int w    = tid >> 6;          // gate id
  const int u0   = blockIdx.x * 16;
  const int r0   = lane & 15;
  const int hi   = lane >> 4;
  const int rb   = hi * 4;
  const int gb   = tid >> 3;          // gate-phase batch row 0..31
  const int j0   = (tid & 7) * 2;     // gate-phase unit pair

  // ---- one-time: B fragments (gate w, units u0+r0, all K) -> registers ----
  bf16x8 breg[32];
#pragma unroll
  for (int kk = 0; kk < 32; ++kk)
    breg[kk] = *(const bf16x8*)(wrT + ((size_t)w * 1024 + u0 + r0) * 1024 + kk * 32 + hi * 8);

  float c0 = 0.f, c1 = 0.f;           // cell state for (gb,j0),(gb,j0+1)
  float xv[8], xvn[8];
#pragma unroll
  for (int m = 0; m < 2; ++m)
#pragma unroll
    for (int r = 0; r < 4; ++r) {
      const size_t off = ((size_t)((m * 16 + rb + r) * 256 + 0)) * 4096 +
                         (size_t)w * 1024 + u0 + r0;
      xv[m * 4 + r] = xg32 ? xgf[off] : bf2f(xgb[off]);
    }

  for (int t = 0; t < 256; ++t) {
    f32x4 acc0 = (f32x4){0.f, 0.f, 0.f, 0.f};
    f32x4 acc1 = acc0;

    if (t > 0) {
      // ---- wait for all WGs' h_{t-1} (monotone flags, no RMW) ----
      const uint32_t target = (uint32_t)(l * 256 + t);
      while (true) {
        uint32_t v = __hip_atomic_load(flags + lane, __ATOMIC_RELAXED,
                                       __HIP_MEMORY_SCOPE_AGENT);
        if (__all(v >= target)) break;
        __builtin_amdgcn_s_sleep(1);
      }

      // ---- coherent gather of full h_{t-1} (64 KB) ----
      f32x4 hreg[16];
#pragma unroll
      for (int k = 0; k < 16; ++k) {
        const int c   = k * 256 + tid;          // 16B chunk id 0..4095
        const int row = c >> 7;                 // batch 0..31
        const int q   = c & 127;                // 16B col chunk
        hreg[k] = ldg_coh16(ys + ((size_t)(row * 256 + t - 1)) * 1024 + q * 8);
      }
      asm volatile("s_waitcnt vmcnt(0)" ::: "memory");
      __builtin_amdgcn_sched_barrier(0);

      // ---- stage into LDS, XOR-swizzled ----
#pragma unroll
      for (int k = 0; k < 16; ++k) {
        const int c   = k * 256 + tid;
        const int row = c >> 7;
        const int q   = c & 127;
        *(f32x4*)(Hs + (size_t)row * 1024 + (size_t)(q ^ (row & 7)) * 8) = hreg[k];
      }
      __syncthreads();   // B1: A panel staged

      // ---- MFMA: A from LDS (swizzled read), B from registers ----
#pragma unroll
      for (int kk = 0; kk < 32; ++kk) {
        const int q  = kk * 4 + hi;
        const int sw = (q ^ (r0 & 7)) * 8;
        bf16x8 a0 = *(const bf16x8*)(Hs + (size_t)r0 * 1024 + sw);
        bf16x8 a1 = *(const bf16x8*)(Hs + (size_t)(16 + r0) * 1024 + sw);
        acc0 = __builtin_amdgcn_mfma_f32_16x16x32_bf16(a0, breg[kk], acc0, 0, 0, 0);
        acc1 = __builtin_amdgcn_mfma_f32_16x16x32_bf16(a1, breg[kk], acc1, 0, 0, 0);
      }
    }

    // prefetch xg for t+1 (drained by B3's vmcnt or next asm vmcnt(0))
    if (t < 255) {
#pragma unroll
      for (int m = 0; m < 2; ++m)
#pragma unroll
        for (int r = 0; r < 4; ++r) {
          const size_t off = ((size_t)((m * 16 + rb + r) * 256 + t + 1)) * 4096 +
                             (size_t)w * 1024 + u0 + r0;
          xvn[m * 4 + r] = xg32 ? xgf[off] : bf2f(xgb[off]);
        }
    }

    // D frag -> gl: col=lane&15 (unit j), row=(lane>>4)*4+reg (batch)
#pragma unroll
    for (int m = 0; m < 2; ++m) {
      f32x4 a = m ? acc1 : acc0;
#pragma unroll
      for (int r = 0; r < 4; ++r)
        gl[w][m * 16 + rb + r][r0] = a[r] + xv[m * 4 + r];
    }
    __syncthreads();   // B2: gl complete across gates

    // gates + cell update (c in regs) + coherent h publish (u32 pairs)
    float hv[2];
#pragma unroll
    for (int jj = 0; jj < 2; ++jj) {
      const int j = j0 + jj;
      const float gi = gl[0][gb][j];
      const float gf = gl[1][gb][j];
      const float gc = gl[2][gb][j];
      const float go = gl[3][gb][j];
      const float i_ = sigmoidf(gi), f_ = sigmoidf(gf);
      const float cd = tanhf(gc),   o_ = sigmoidf(go);
      float& c = jj ? c1 : c0;
      c = f_ * c + i_ * cd;
      hv[jj] = o_ * tanhf(c);
      if (t == 255) {
        out[(size_t)l * 32768 + (size_t)gb * 1024 + u0 + j]       = hv[jj];
        out[(size_t)(4 + l) * 32768 + (size_t)gb * 1024 + u0 + j] = c;
      }
    }
    const uint32_t pk = (uint32_t)f2bf(hv[0]) | ((uint32_t)f2bf(hv[1]) << 16);
    __hip_atomic_store((uint32_t*)(ys + ((size_t)(gb * 256 + t)) * 1024 + u0 + j0),
                       pk, __ATOMIC_RELAXED, __HIP_MEMORY_SCOPE_AGENT);

    if (t < 255) {
      __syncthreads();   // B3: all waves' h stores ack'd (vmcnt drain)
      if (tid == 0)
        __hip_atomic_store(flags + blockIdx.x, (uint32_t)(l * 256 + t + 1),
                           __ATOMIC_RELAXED, __HIP_MEMORY_SCOPE_AGENT);
    }
#pragma unroll
    for (int i = 0; i < 8; ++i) xv[i] = xvn[i];
  }
}

// seq += ys (residual); refresh bf16 copy of seq
__global__ void seq_update_kernel(float* __restrict__ seqf, u16* __restrict__ seqb,
                                  const u16* __restrict__ ys, int n) {
  int i = (blockIdx.x * blockDim.x + threadIdx.x) * 4;
  if (i + 3 < n) {
    f32x4 s = *(f32x4*)(seqf + i);
    uint64_t yv = *(const uint64_t*)(ys + i);
    s[0] += bf2f((u16)(yv & 0xFFFF));
    s[1] += bf2f((u16)((yv >> 16) & 0xFFFF));
    s[2] += bf2f((u16)((yv >> 32) & 0xFFFF));
    s[3] += bf2f((u16)((yv >> 48) & 0xFFFF));
    *(f32x4*)(seqf + i) = s;
    uint64_t pk = (uint64_t)f2bf(s[0]) | ((uint64_t)f2bf(s[1]) << 16) |
                  ((uint64_t)f2bf(s[2]) << 32) | ((uint64_t)f2bf(s[3]) << 48);
    *(uint64_t*)(seqb + i) = pk;
  }
}

// ---------------------------------------------------------------------------
extern "C" void kernel_launch(void* const* d_in, const int* in_sizes, int n_in,
                              void* d_out, int out_size, void* d_ws, size_t ws_size,
                              hipStream_t stream) {
  const float* x     = (const float*)d_in[0];   // (32,256,512)
  const float* Wskip = (const float*)d_in[1];   // (512,1024)
  const float* Wk    = (const float*)d_in[2];   // (4,1024,4096)
  const float* Wr    = (const float*)d_in[3];   // (4,1024,4096)
  const float* bias  = (const float*)d_in[4];   // (4,4096)
  float* out = (float*)d_out;

  char* ws = (char*)d_ws;
  size_t o = 0;
  auto carve = [&](size_t bytes) -> char* {
    char* p = ws + o;
    o += (bytes + 255) & ~(size_t)255;
    return p;
  };
  u16*      xbf   = (u16*)     carve((size_t)8192 * 512 * 2);
  u16*      wskT  = (u16*)     carve((size_t)1024 * 512 * 2);
  u16*      wkT   = (u16*)     carve((size_t)4 * 4096 * 1024 * 2);
  u16*      wrT   = (u16*)     carve((size_t)4 * 4096 * 1024 * 2);
  float*    seqf  = (float*)   carve((size_t)8192 * 1024 * 4);
  u16*      seqb  = (u16*)     carve((size_t)8192 * 1024 * 2);
  u16*      ysb   = (u16*)     carve((size_t)8192 * 1024 * 2);
  uint32_t* flags = (uint32_t*)carve((size_t)64 * 4);
  // xg: prefer f32 storage (accuracy) if workspace allows; else bf16
  const int xg32 = (ws_size >= o + (size_t)8192 * 4096 * 4 + 512) ? 1 : 0;
  float* xgf = nullptr;
  u16*   xgb = nullptr;
  if (xg32) xgf = (float*)carve((size_t)8192 * 4096 * 4);
  else      xgb = (u16*)  carve((size_t)8192 * 4096 * 2);

  // ---- prep ----
  hipMemsetAsync(flags, 0, 64 * 4, stream);
  convert_bf16_kernel<<<4096, 256, 0, stream>>>(x, xbf, 8192 * 512);
  dim3 tb(32, 32);
  transpose_to_bf16<<<dim3(1024 / 32, 512 / 32), tb, 0, stream>>>(Wskip, wskT, 512, 1024);
  for (int l = 0; l < 4; ++l) {
    transpose_to_bf16<<<dim3(4096 / 32, 1024 / 32), tb, 0, stream>>>(
        Wk + (size_t)l * 1024 * 4096, wkT + (size_t)l * 4096 * 1024, 1024, 4096);
    transpose_to_bf16<<<dim3(4096 / 32, 1024 / 32), tb, 0, stream>>>(
        Wr + (size_t)l * 1024 * 4096, wrT + (size_t)l * 4096 * 1024, 1024, 4096);
  }

  // ---- skip projection: seq = x @ W_skip ----
  gemm_bt_kernel<<<dim3(1024 / 128, 8192 / 128), 256, 0, stream>>>(
      xbf, wskT, nullptr, seqf, seqb, 8192, 1024, 512, 0);

  // ---- layers ----
  for (int l = 0; l < 4; ++l) {
    gemm_bt_kernel<<<dim3(4096 / 128, 8192 / 128), 256, 0, stream>>>(
        seqb, wkT + (size_t)l * 4096 * 1024, bias + (size_t)l * 4096,
        xgf, xgb, 8192, 4096, 1024, xg32 ? 2 : 1);
    lstm_layer_kernel<<<NWG, 256, 0, stream>>>(xgb, xgf, xg32,
                                               wrT + (size_t)l * 4096 * 1024,
                                               ysb, out, flags, l);
    if (l < 3)
      seq_update_kernel<<<8192, 256, 0, stream>>>(seqf, seqb, ysb, 8192 * 1024);
  }
}